// Round 2
// baseline (555.848 us; speedup 1.0000x reference)
//
#include <hip/hip_runtime.h>

// AdaPool2D: 2x2 stride-2 window, blend of exp-softmax pooling and
// Dice-Sorensen-softmax pooling.
//   inputs: [B=32, W=224, H=224, C=64] fp32 (C contiguous innermost)
//   mask:   [1] fp32 blend scalar
//   out:    [B, 112, 112, 64] fp32
//
// R2 design: fully-contiguous wave loads.
//   Each wave handles 4 consecutive input H-rows (h0..h0+3) x 64 channels
//   for both W-rows (2wo, 2wo+1) of one output row-block:
//     load A = row 2wo  : lane L reads float4 at (h0*64 + L*4) -> 1 KB contiguous
//     load B = row 2wo+1: same offsets                          -> 1 KB contiguous
//   __shfl_xor(.,16) swaps h-neighbors (lane bit 4 = h parity), then every
//   lane holds the full 2x2 window for (ho = h0/2 + (lane>>5&1), c4 = lane&15).
//   Lanes with odd h compute duplicates (compute is cheap); even-h lanes store
//   512 B contiguous per wave.

constexpr int Bn = 32;
constexpr int Wd = 224;
constexpr int Hd = 224;
constexpr int Cd = 64;
constexpr int Wo = 112;
constexpr int Ho = 112;
constexpr int HC = Hd * Cd;                    // 14336 floats: W-row stride
constexpr int WAVES_PER_WO = Hd / 4;           // 56 waves cover one (b,wo)
constexpr int TOTAL_WAVES = Bn * Wo * WAVES_PER_WO;  // 200,704
constexpr int BLOCKS = TOTAL_WAVES / 4;        // 50,176 (256-thread blocks, exact)

__global__ __launch_bounds__(256)
void adapool2d_kernel(const float* __restrict__ in,
                      const float* __restrict__ mask,
                      float* __restrict__ out) {
    const int lane = threadIdx.x & 63;
    const int wv   = (blockIdx.x << 2) | (threadIdx.x >> 6);

    const int hblk = wv % WAVES_PER_WO;
    int t          = wv / WAVES_PER_WO;
    const int wo   = t % Wo;
    const int b    = t / Wo;
    const int h0   = hblk * 4;

    const float m  = mask[0];
    const float m1 = 1.0f - m;

    // Fully coalesced: lane L -> byte offset L*16 within a 1 KB span.
    const float* ptop = in + (size_t)(b * Wd + 2 * wo) * HC + h0 * Cd + lane * 4;
    const float* pbot = ptop + HC;
    float4 At = *reinterpret_cast<const float4*>(ptop);
    float4 Bt = *reinterpret_cast<const float4*>(pbot);

    // Exchange with h-neighbor (lane ^ 16 flips h parity, same c4).
    float4 Ax, Bx;
    Ax.x = __shfl_xor(At.x, 16); Ax.y = __shfl_xor(At.y, 16);
    Ax.z = __shfl_xor(At.z, 16); Ax.w = __shfl_xor(At.w, 16);
    Bx.x = __shfl_xor(Bt.x, 16); Bx.y = __shfl_xor(Bt.y, 16);
    Bx.z = __shfl_xor(Bt.z, 16); Bx.w = __shfl_xor(Bt.w, 16);

    const bool odd = (lane & 16) != 0;   // h parity of this lane's loaded rows
    float4 v00 = odd ? Ax : At;   // (2wo  , 2ho  )
    float4 v01 = odd ? At : Ax;   // (2wo  , 2ho+1)
    float4 v10 = odd ? Bx : Bt;   // (2wo+1, 2ho  )
    float4 v11 = odd ? Bt : Bx;   // (2wo+1, 2ho+1)

    float q0[4] = {v00.x, v00.y, v00.z, v00.w};
    float q1[4] = {v01.x, v01.y, v01.z, v01.w};
    float q2[4] = {v10.x, v10.y, v10.z, v10.w};
    float q3[4] = {v11.x, v11.y, v11.z, v11.w};
    float r[4];

#pragma unroll
    for (int k = 0; k < 4; ++k) {
        float a  = q0[k], bb = q1[k], cc = q2[k], dd = q3[k];

        // exponential-maximum pooling: sum(p * softmax(p))
        float ea = __expf(a), eb = __expf(bb), ec = __expf(cc), ed = __expf(dd);
        float inv_se = __builtin_amdgcn_rcpf(ea + eb + ec + ed);
        float em = (a * ea + bb * eb + cc * ec + dd * ed) * inv_se;

        // eDSCW pooling: dsc = 2*avg*p / (avg^2 + p^2), softmax over window
        float avg  = 0.25f * (a + bb + cc + dd);
        float avg2 = avg * avg;
        float ta   = 2.0f * avg;
        float da = ta * a  * __builtin_amdgcn_rcpf(avg2 + a  * a);
        float db = ta * bb * __builtin_amdgcn_rcpf(avg2 + bb * bb);
        float dc = ta * cc * __builtin_amdgcn_rcpf(avg2 + cc * cc);
        float de = ta * dd * __builtin_amdgcn_rcpf(avg2 + dd * dd);
        float fa = __expf(da), fb = __expf(db), fc = __expf(dc), fd = __expf(de);
        float inv_sd = __builtin_amdgcn_rcpf(fa + fb + fc + fd);
        float dp = (a * fa + bb * fb + cc * fc + dd * fd) * inv_sd;

        r[k] = em * m + dp * m1;
    }

    if (!odd) {
        const int ho = (h0 >> 1) + ((lane >> 5) & 1);
        const int c4 = lane & 15;
        float4 o = make_float4(r[0], r[1], r[2], r[3]);
        reinterpret_cast<float4*>(out)[(size_t)((b * Wo + wo) * Ho + ho) * 16 + c4] = o;
    }
}

extern "C" void kernel_launch(void* const* d_in, const int* in_sizes, int n_in,
                              void* d_out, int out_size, void* d_ws, size_t ws_size,
                              hipStream_t stream) {
    const float* in   = (const float*)d_in[0];
    const float* mask = (const float*)d_in[1];
    float* out        = (float*)d_out;

    adapool2d_kernel<<<BLOCKS, 256, 0, stream>>>(in, mask, out);
}